// Round 1
// 1401.643 us; speedup vs baseline: 1.1527x; 1.1527x over previous
//
#include <hip/hip_runtime.h>
#include <hip/hip_bf16.h>
#include <math.h>

// Problem constants
#define D_MODEL 2048
#define D_STATE 16
#define D_CONV  4
#define DT_RANK 128
#define D_INNER 4096
#define BATCH   4
#define SEQLEN  2048
#define BL      (BATCH * SEQLEN)   // 8192 tokens

// Chunked-scan geometry
#define NCHUNK 4
#define CHUNK  (SEQLEN / NCHUNK)   // 512 steps per chunk
#define SCH    32                  // steps per LDS tile
#define NTILE  (CHUNK / SCH)       // 16 tiles per chunk

typedef __hip_bfloat16 bf16;
typedef __attribute__((ext_vector_type(8))) short  short8;   // 8 bf16 (4 VGPRs)
typedef __attribute__((ext_vector_type(4))) float  f32x4;

__device__ __forceinline__ float bf2f(bf16 v) { return __bfloat162float(v); }
__device__ __forceinline__ bf16  f2bf(float v) { return __float2bfloat16(v); }
__device__ __forceinline__ float us2f(unsigned short v) {
    return __uint_as_float((unsigned)v << 16);
}
__device__ __forceinline__ void st1(float* p, float v) { *p = v; }
__device__ __forceinline__ void st1(bf16* p, float v)  { *p = f2bf(v); }
__device__ __forceinline__ float fast_rcp(float x) { return __builtin_amdgcn_rcpf(x); }

__device__ __forceinline__ void async_cp16(const void* g, void* l) {
    __builtin_amdgcn_global_load_lds(
        (const __attribute__((address_space(1))) void*)g,
        (__attribute__((address_space(3))) void*)l, 16, 0, 0);
}

// ---------------------------------------------------------------------------
// bf16 MFMA NT GEMM: C[M,N] = sum_k A[m,k]*B[n,k].
// 128x128 tile, BK=64, 256 threads (4 waves 2x2), 4x4 16x16x32 frags/wave.
// Epilogues: 0 = plain store; 1 = x_proj split (dt_lr bf16 / BC fp32);
//            2 = softplus(acc + bias[col]) -> bf16
// ---------------------------------------------------------------------------
template <int EPI, typename TC>
__global__ __launch_bounds__(256) void gemm_mfma_nt(
    const bf16* __restrict__ A, const bf16* __restrict__ B,
    TC* __restrict__ C, int M, int N, int K, int lda, int ldb, int ldc,
    const float* __restrict__ bias, bf16* __restrict__ aux,
    float* __restrict__ aux2)
{
    __shared__ bf16 As[128][64];   // 16 KB
    __shared__ bf16 Bs[128][64];   // 16 KB

    const int tid  = threadIdx.x;
    const int lane = tid & 63;
    const int wave = tid >> 6;          // 0..3
    const int wm   = (wave >> 1) * 64;
    const int wn   = (wave & 1) * 64;

    const int m0 = blockIdx.x * 128;
    const int n0 = blockIdx.y * 128;

    f32x4 acc[4][4] = {};

    const int srow = lane >> 3;
    const int scol = (lane & 7) * 8;

    for (int k0 = 0; k0 < K; k0 += 64) {
        __syncthreads();
#pragma unroll
        for (int i = 0; i < 4; ++i) {
            int seg = wave * 4 + i;
            int row = seg * 8 + srow;
            async_cp16(A + (size_t)(m0 + row) * lda + k0 + scol, &As[seg * 8][0]);
            async_cp16(B + (size_t)(n0 + row) * ldb + k0 + scol, &Bs[seg * 8][0]);
        }
        __syncthreads();

#pragma unroll
        for (int kk = 0; kk < 64; kk += 32) {
            short8 a[4], b[4];
            const int fr = lane & 15;
            const int fk = kk + (lane >> 4) * 8;
#pragma unroll
            for (int i = 0; i < 4; ++i) {
                a[i] = *(const short8*)&As[wm + i * 16 + fr][fk];
                b[i] = *(const short8*)&Bs[wn + i * 16 + fr][fk];
            }
#pragma unroll
            for (int i = 0; i < 4; ++i)
#pragma unroll
                for (int j = 0; j < 4; ++j)
                    acc[i][j] = __builtin_amdgcn_mfma_f32_16x16x32_bf16(
                        a[i], b[j], acc[i][j], 0, 0, 0);
        }
    }

    // C/D: col = lane&15, row = (lane>>4)*4 + reg   [m89-verified]
#pragma unroll
    for (int i = 0; i < 4; ++i) {
        int row = m0 + wm + i * 16 + (lane >> 4) * 4;
#pragma unroll
        for (int j = 0; j < 4; ++j) {
            int col = n0 + wn + j * 16 + (lane & 15);
#pragma unroll
            for (int r = 0; r < 4; ++r) {
                float v = acc[i][j][r];
                if (EPI == 0) {
                    st1(C + (size_t)(row + r) * ldc + col, v);
                } else if (EPI == 1) {
                    if (col < DT_RANK)
                        aux[(size_t)(row + r) * DT_RANK + col] = f2bf(v);
                    else if (col < DT_RANK + 2 * D_STATE)
                        aux2[(size_t)(row + r) * (2 * D_STATE) + (col - DT_RANK)] = v;
                } else {  // EPI == 2: softplus(acc + bias)
                    float x  = v + bias[col];
                    float sp = fmaxf(x, 0.f) + __logf(1.f + __expf(-fabsf(x)));
                    ((bf16*)C)[(size_t)(row + r) * ldc + col] = f2bf(sp);
                }
            }
        }
    }
}

// ---------------------------------------------------------------------------
// fp32 -> bf16 conversion (4 elems/thread); n must be a multiple of 1024.
// ---------------------------------------------------------------------------
__global__ void cvt_f32_bf16(const float* __restrict__ src,
                             bf16* __restrict__ dst, int n)
{
    int i = (blockIdx.x * blockDim.x + threadIdx.x) * 4;
    if (i >= n) return;
    float4 v = *(const float4*)(src + i);
    bf16 o[4] = { f2bf(v.x), f2bf(v.y), f2bf(v.z), f2bf(v.w) };
    *(ushort4*)(dst + i) = *(ushort4*)o;
}

// W_x (160 x 4096 fp32) -> zero-padded 256 x 4096 bf16
__global__ void cvt_pad_wx(const float* __restrict__ src, bf16* __restrict__ dst)
{
    int i = (blockIdx.x * blockDim.x + threadIdx.x) * 4;
    if (i >= 256 * D_INNER) return;
    int row = i / D_INNER;
    bf16 o[4] = {};
    if (row < DT_RANK + 2 * D_STATE) {
        float4 v = *(const float4*)(src + i);
        o[0] = f2bf(v.x); o[1] = f2bf(v.y); o[2] = f2bf(v.z); o[3] = f2bf(v.w);
    }
    *(ushort4*)(dst + i) = *(ushort4*)o;
}

// ---------------------------------------------------------------------------
// Depthwise causal conv1d (width 4) + bias + SiLU.  bf16 in/out, fp32 math.
// ---------------------------------------------------------------------------
__global__ void conv_silu(const bf16* __restrict__ X,
                          const float* __restrict__ conv_w,
                          const float* __restrict__ conv_b,
                          bf16* __restrict__ xact)
{
    unsigned idx = blockIdx.x * blockDim.x + threadIdx.x;
    if (idx >= (unsigned)BL * D_INNER) return;
    int c = idx & (D_INNER - 1);
    unsigned bl = idx >> 12;
    int l = bl & (SEQLEN - 1);
    int b = bl >> 11;

    float acc = conv_b[c];
#pragma unroll
    for (int t = 0; t < D_CONV; ++t) {
        int ll = l - (D_CONV - 1) + t;
        if (ll >= 0)
            acc = fmaf(bf2f(X[((size_t)b * SEQLEN + ll) * D_INNER + c]),
                       conv_w[c * D_CONV + t], acc);
    }
    xact[(size_t)bl * D_INNER + c] = f2bf(acc * fast_rcp(1.f + __expf(-acc)));
}

// ---------------------------------------------------------------------------
// Chunked selective scan.  The linear recurrence h_t = e_t*h_{t-1} + b_t is
// split into NCHUNK=4 chunks of 512 steps:
//   pass 1 (scan_part1): per chunk c<NCHUNK-1, local final state hL (h0=0)
//                        and sum(delta) (since prod exp(dl*A) = exp(A*sum dl)).
//   pass 2 (scan_combine): tiny serial combine over chunks -> true initial
//                        state per chunk, stored in-place over hL.
//   pass 3 (scan_main):  full scan + y epilogue per chunk from true h_init.
// Grid goes 512 -> 2048 blocks and LDS tile shrinks to 32 steps (20 KB) so
// 8 blocks/CU fit -> ~100% wave occupancy (vs 23%): latency-bound -> issue-bound.
// Scratch (3.2 MB) lives in the dead dtlr+wxp tail region.
// ---------------------------------------------------------------------------
__global__ __launch_bounds__(256, 8) void scan_part1(
    const bf16* __restrict__ U,      // xact   (BL, D_INNER)
    const bf16* __restrict__ DLT,    // delta  (BL, D_INNER)
    const float* __restrict__ BC,    // (BL, 32): B[16] then C[16]
    const float* __restrict__ A_log,
    float2* __restrict__ Hscr,       // (NCHUNK-1, BATCH, D_INNER, 8)
    float*  __restrict__ Sscr)       // (NCHUNK-1, BATCH, D_INNER)
{
    __shared__ unsigned short Us[2][SCH][32];   // 4 KB
    __shared__ unsigned short Ds[2][SCH][32];   // 4 KB
    __shared__ float          Bs[2][SCH][16];   // 4 KB

    const int b    = blockIdx.y;
    const int c    = blockIdx.z;               // chunk 0..NCHUNK-2
    const int d0   = blockIdx.x * 32;
    const int lane = threadIdx.x & 63;
    const int wave = threadIdx.x >> 6;
    const int sub  = lane & 7;                 // state pair {2sub, 2sub+1}
    const int grp  = lane >> 3;
    const int ci   = wave * 8 + grp;           // channel within block
    const int d    = d0 + ci;

    const float2 al = *(const float2*)&A_log[(size_t)d * D_STATE + 2 * sub];
    const float A0 = -__expf(al.x), A1 = -__expf(al.y);

    const size_t base = (size_t)b * SEQLEN + (size_t)c * CHUNK;

    const int r16 = lane >> 2;                 // 0..15
    const int c8  = (lane & 3) * 8;            // bf16 col (16 B)
    const int c4f = (lane & 3) * 4;            // float col (16 B) for B tile

    auto stage = [&](int bb, int l0) {
        if (wave == 0) {
#pragma unroll
            for (int i = 0; i < 2; ++i) {
                int row = i * 16 + r16;
                async_cp16(U + (base + l0 + row) * (size_t)D_INNER + d0 + c8,
                           &Us[bb][i * 16][0]);
            }
        } else if (wave == 1) {
#pragma unroll
            for (int i = 0; i < 2; ++i) {
                int row = i * 16 + r16;
                async_cp16(DLT + (base + l0 + row) * (size_t)D_INNER + d0 + c8,
                           &Ds[bb][i * 16][0]);
            }
        } else if (wave == 2) {
#pragma unroll
            for (int i = 0; i < 2; ++i) {
                int row = i * 16 + r16;
                async_cp16(BC + (base + l0 + row) * (2 * D_STATE) + c4f,
                           &Bs[bb][i * 16][0]);
            }
        }
    };

    float h0 = 0.f, h1 = 0.f, sdl = 0.f;

    stage(0, 0);
    __syncthreads();   // tile 0 resident

    for (int t = 0; t < NTILE; ++t) {
        const int cur = t & 1, nxt = cur ^ 1;
        if (t + 1 < NTILE) stage(nxt, (t + 1) * SCH);

        for (int l = 0; l < SCH; ++l) {
            float u  = us2f(Us[cur][l][ci]);
            float dl = us2f(Ds[cur][l][ci]);
            float e0 = __expf(dl * A0);
            float e1 = __expf(dl * A1);
            float du = dl * u;
            float2 Bv = *(const float2*)&Bs[cur][l][2 * sub];
            h0 = fmaf(h0, e0, du * Bv.x);
            h1 = fmaf(h1, e1, du * Bv.y);
            sdl += dl;
        }
        __syncthreads();
    }

    const size_t idx = (size_t)(c * BATCH + b) * D_INNER + d;
    Hscr[idx * 8 + sub] = make_float2(h0, h1);
    if (sub == 0) Sscr[idx] = sdl;
}

__global__ void scan_combine(float2* __restrict__ Hscr,
                             const float* __restrict__ Sscr,
                             const float* __restrict__ A_log)
{
    int tid = blockIdx.x * blockDim.x + threadIdx.x;   // (b, d, sub)
    if (tid >= BATCH * D_INNER * 8) return;
    const int sub = tid & 7;
    const int d   = (tid >> 3) & (D_INNER - 1);
    const int b   = tid >> 15;

    const float2 al = *(const float2*)&A_log[(size_t)d * D_STATE + 2 * sub];
    const float A0 = -__expf(al.x), A1 = -__expf(al.y);

    float H0 = 0.f, H1 = 0.f;   // Hinit for chunk 0
#pragma unroll
    for (int c = 0; c < NCHUNK - 1; ++c) {
        const size_t idx = (size_t)(c * BATCH + b) * D_INNER + d;
        float2 hl = Hscr[idx * 8 + sub];
        float  s  = Sscr[idx];
        // Hinit[c+1] = hL[c] + exp(A*sum_dl[c]) * Hinit[c]; store at slot c
        H0 = fmaf(H0, __expf(A0 * s), hl.x);
        H1 = fmaf(H1, __expf(A1 * s), hl.y);
        Hscr[idx * 8 + sub] = make_float2(H0, H1);
    }
}

__global__ __launch_bounds__(256, 8) void scan_main(
    const bf16* __restrict__ U,      // xact   (BL, D_INNER)
    const bf16* __restrict__ DLT,    // delta  (BL, D_INNER)
    const bf16* __restrict__ Z,      // z      (BL, D_INNER)
    const float* __restrict__ BC,    // (BL, 32): B[16] then C[16]
    const float* __restrict__ A_log,
    const float* __restrict__ Dp,
    const float2* __restrict__ Hscr, // chunk init states (slot c-1 for chunk c)
    bf16* __restrict__ Y)            // output y (may alias Z)
{
    __shared__ unsigned short Us[2][SCH][32];   // 4 KB
    __shared__ unsigned short Ds[2][SCH][32];   // 4 KB
    __shared__ unsigned short Zs[2][SCH][32];   // 4 KB
    __shared__ float         BCs[2][SCH][32];   // 8 KB

    const int b    = blockIdx.y;
    const int c    = blockIdx.z;               // chunk 0..NCHUNK-1
    const int d0   = blockIdx.x * 32;
    const int lane = threadIdx.x & 63;
    const int wave = threadIdx.x >> 6;
    const int sub  = lane & 7;
    const int grp  = lane >> 3;
    const int ci   = wave * 8 + grp;
    const int d    = d0 + ci;

    const float2 al = *(const float2*)&A_log[(size_t)d * D_STATE + 2 * sub];
    const float A0 = -__expf(al.x), A1 = -__expf(al.y);
    const float Dv = Dp[d];

    const size_t base = (size_t)b * SEQLEN + (size_t)c * CHUNK;

    const int r16 = lane >> 2;                 // 0..15 (bf16 tiles)
    const int c8  = (lane & 3) * 8;
    const int r8  = lane >> 3;                 // 0..7  (BC tile)
    const int c4  = (lane & 7) * 4;

    auto stage = [&](int bb, int l0) {
        if (wave == 0) {
#pragma unroll
            for (int i = 0; i < 2; ++i) {
                int row = i * 16 + r16;
                async_cp16(U + (base + l0 + row) * (size_t)D_INNER + d0 + c8,
                           &Us[bb][i * 16][0]);
            }
        } else if (wave == 1) {
#pragma unroll
            for (int i = 0; i < 2; ++i) {
                int row = i * 16 + r16;
                async_cp16(DLT + (base + l0 + row) * (size_t)D_INNER + d0 + c8,
                           &Ds[bb][i * 16][0]);
            }
        } else if (wave == 2) {
#pragma unroll
            for (int i = 0; i < 2; ++i) {
                int row = i * 16 + r16;
                async_cp16(Z + (base + l0 + row) * (size_t)D_INNER + d0 + c8,
                           &Zs[bb][i * 16][0]);
            }
        } else {
#pragma unroll
            for (int i = 0; i < 4; ++i) {
                int row = i * 8 + r8;
                async_cp16(BC + (base + l0 + row) * (2 * D_STATE) + c4,
                           &BCs[bb][i * 8][0]);
            }
        }
    };

    float h0 = 0.f, h1 = 0.f;
    if (c > 0) {
        float2 hi = Hscr[((size_t)((c - 1) * BATCH + b) * D_INNER + d) * 8 + sub];
        h0 = hi.x; h1 = hi.y;
    }

    stage(0, 0);
    __syncthreads();   // tile 0 resident

    for (int t = 0; t < NTILE; ++t) {
        const int cur = t & 1, nxt = cur ^ 1;
        if (t + 1 < NTILE) stage(nxt, (t + 1) * SCH);

        for (int l = 0; l < SCH; ++l) {
            float u  = us2f(Us[cur][l][ci]);
            float dl = us2f(Ds[cur][l][ci]);
            float e0 = __expf(dl * A0);
            float e1 = __expf(dl * A1);
            float du = dl * u;
            float2 Bv = *(const float2*)&BCs[cur][l][2 * sub];
            float2 Cv = *(const float2*)&BCs[cur][l][D_STATE + 2 * sub];
            h0 = fmaf(h0, e0, du * Bv.x);
            h1 = fmaf(h1, e1, du * Bv.y);
            float p = fmaf(h1, Cv.y, h0 * Cv.x);
            p += __shfl_xor(p, 1, 8);
            p += __shfl_xor(p, 2, 8);
            p += __shfl_xor(p, 4, 8);
            if (sub == 0) {
                float z = us2f(Zs[cur][l][ci]);
                float g = z * fast_rcp(1.f + __expf(-z));
                Y[(base + t * SCH + l) * (size_t)D_INNER + d] =
                    f2bf((p + Dv * u) * g);
            }
        }
        __syncthreads();   // all waves done with cur; nxt stage drained
    }
}

// ---------------------------------------------------------------------------
// Workspace (total exactly 139,460,608 B — proven safe):
//   buf1  [  0,  64Mi) bf16 : X -> delta -> W_out_bf16
//   buf2  [64Mi, 128Mi) bf16 : Z -> y (in place, via scan)
//   tail  [128Mi, +5MiB): BCbuf fp32 (1 MiB) | dtlr bf16 (2 MiB) |
//                         wxp bf16 (2 MiB; W_dt bf16 reuses it)
//   After phase 4 the dtlr+wxp 4 MiB region is dead -> chunked-scan scratch
//   (Hscr 3 MiB + Sscr 0.19 MiB) lives there.
// d_out doubles as scratch: hs_bf16 (32 MiB) + W_in_bf16 (32 MiB) during
// in_proj; then xact bf16 (64 MiB) until out_proj writes the final fp32.
// ---------------------------------------------------------------------------
extern "C" void kernel_launch(void* const* d_in, const int* in_sizes, int n_in,
                              void* d_out, int out_size, void* d_ws, size_t ws_size,
                              hipStream_t stream)
{
    const float* hs      = (const float*)d_in[0];
    const float* W_in    = (const float*)d_in[1];
    const float* conv_w  = (const float*)d_in[2];
    const float* conv_b  = (const float*)d_in[3];
    const float* W_x     = (const float*)d_in[4];
    const float* W_dt    = (const float*)d_in[5];
    const float* dt_bias = (const float*)d_in[6];
    const float* A_log   = (const float*)d_in[7];
    const float* Dp      = (const float*)d_in[8];
    const float* W_out   = (const float*)d_in[9];
    float* out = (float*)d_out;

    const size_t nBig = (size_t)BL * D_INNER;            // 33,554,432
    const size_t need = 2 * nBig * sizeof(bf16)
                      + (size_t)BL * 160 * sizeof(float);
    if (ws_size < need) {
        hipMemsetAsync(d_out, 0, (size_t)out_size * sizeof(float), stream);
        return;
    }

    bf16*  buf1  = (bf16*)d_ws;                          // 64 MiB
    bf16*  buf2  = buf1 + nBig;                          // 64 MiB
    float* BCbuf = (float*)(buf2 + nBig);                // 1 MiB (BL x 32 fp32)
    bf16*  dtlr  = (bf16*)(BCbuf + (size_t)BL * 2 * D_STATE); // 2 MiB
    bf16*  wxp   = dtlr + (size_t)BL * DT_RANK;          // 2 MiB
    bf16*  wdtb  = wxp;                                  // reuse (phase 4)

    // chunked-scan scratch overlays dtlr+wxp (dead after phase 4): 3.34 MiB
    float2* Hscr = (float2*)dtlr;
    float*  Sscr = (float*)(Hscr + (size_t)(NCHUNK - 1) * BATCH * D_INNER * 8);

    const int nHS = BL * D_MODEL;                        // 16,777,216
    const int nWI = 2 * D_INNER * D_MODEL;               // 16,777,216
    const int nWH = D_INNER * D_MODEL;                   // 8,388,608
    bf16* hsb  = (bf16*)d_out;                           // 32 MiB
    bf16* wb   = hsb + nHS;                              // 32 MiB
    bf16* xact = (bf16*)d_out;                           // after hsb/wb die

    // --- Phase 1: in_proj (bf16 MFMA) ------------------------------------
    cvt_f32_bf16<<<nHS / 1024, 256, 0, stream>>>(hs, hsb, nHS);
    cvt_f32_bf16<<<nWI / 1024, 256, 0, stream>>>(W_in, wb, nWI);
    gemm_mfma_nt<0, bf16><<<dim3(BL / 128, D_INNER / 128), 256, 0, stream>>>(
        hsb, wb + (size_t)nWH, buf2, BL, D_INNER, D_MODEL,
        D_MODEL, D_MODEL, D_INNER, nullptr, nullptr, nullptr);
    gemm_mfma_nt<0, bf16><<<dim3(BL / 128, D_INNER / 128), 256, 0, stream>>>(
        hsb, wb, buf1, BL, D_INNER, D_MODEL,
        D_MODEL, D_MODEL, D_INNER, nullptr, nullptr, nullptr);

    // --- Phase 2: conv + SiLU -> xact (d_out; hsb/wb dead) ---------------
    conv_silu<<<(BL * D_INNER + 255) / 256, 256, 0, stream>>>(
        buf1, conv_w, conv_b, xact);

    // --- Phase 3: x_proj (MFMA, padded N=256) -> dtlr bf16 + BCbuf fp32 --
    cvt_pad_wx<<<(256 * D_INNER) / 1024, 256, 0, stream>>>(W_x, wxp);
    gemm_mfma_nt<1, float><<<dim3(BL / 128, 2), 256, 0, stream>>>(
        xact, wxp, (float*)nullptr, BL, 256, D_INNER,
        D_INNER, D_INNER, 0, nullptr, dtlr, BCbuf);

    // --- Phase 4: dt_proj (MFMA) + fused softplus(+bias) -> delta (buf1) -
    cvt_f32_bf16<<<(D_INNER * DT_RANK) / 1024, 256, 0, stream>>>(W_dt, wdtb,
                                                                 D_INNER * DT_RANK);
    gemm_mfma_nt<2, bf16><<<dim3(BL / 128, D_INNER / 128), 256, 0, stream>>>(
        dtlr, wdtb, buf1, BL, D_INNER, DT_RANK,
        DT_RANK, DT_RANK, D_INNER, dt_bias, nullptr, nullptr);

    // --- Phase 5: chunked scan (silu(z) fused) -> y in buf2 --------------
    scan_part1<<<dim3(D_INNER / 32, BATCH, NCHUNK - 1), 256, 0, stream>>>(
        xact, buf1, BCbuf, A_log, Hscr, Sscr);
    scan_combine<<<(BATCH * D_INNER * 8) / 256, 256, 0, stream>>>(
        Hscr, Sscr, A_log);
    scan_main<<<dim3(D_INNER / 32, BATCH, NCHUNK), 256, 0, stream>>>(
        xact, buf1, buf2, BCbuf, A_log, Dp, Hscr, buf2);

    // --- Phase 6: out_proj (MFMA).  W_out -> buf1 (delta dead) -----------
    cvt_f32_bf16<<<nWH / 1024, 256, 0, stream>>>(W_out, buf1, nWH);
    gemm_mfma_nt<0, float><<<dim3(BL / 128, D_MODEL / 128), 256, 0, stream>>>(
        buf2, buf1, out, BL, D_MODEL, D_INNER,
        D_INNER, D_INNER, D_MODEL, nullptr, nullptr, nullptr);
}

// Round 2
// 1350.646 us; speedup vs baseline: 1.1962x; 1.0378x over previous
//
#include <hip/hip_runtime.h>
#include <hip/hip_bf16.h>
#include <math.h>

// Problem constants
#define D_MODEL 2048
#define D_STATE 16
#define D_CONV  4
#define DT_RANK 128
#define D_INNER 4096
#define BATCH   4
#define SEQLEN  2048
#define BL      (BATCH * SEQLEN)   // 8192 tokens

// Chunked-scan geometry
#define NCHUNK 4
#define CHUNK  (SEQLEN / NCHUNK)   // 512 steps per chunk
#define SCH    32                  // steps per LDS tile
#define NTILE  (CHUNK / SCH)       // 16 tiles per chunk

typedef __hip_bfloat16 bf16;
typedef __attribute__((ext_vector_type(8))) short  short8;   // 8 bf16 (4 VGPRs)
typedef __attribute__((ext_vector_type(4))) float  f32x4;

__device__ __forceinline__ float bf2f(bf16 v) { return __bfloat162float(v); }
__device__ __forceinline__ bf16  f2bf(float v) { return __float2bfloat16(v); }
__device__ __forceinline__ float us2f(unsigned short v) {
    return __uint_as_float((unsigned)v << 16);
}
__device__ __forceinline__ void st1(float* p, float v) { *p = v; }
__device__ __forceinline__ void st1(bf16* p, float v)  { *p = f2bf(v); }
__device__ __forceinline__ float fast_rcp(float x) { return __builtin_amdgcn_rcpf(x); }

__device__ __forceinline__ void async_cp16(const void* g, void* l) {
    __builtin_amdgcn_global_load_lds(
        (const __attribute__((address_space(1))) void*)g,
        (__attribute__((address_space(3))) void*)l, 16, 0, 0);
}

// Sum across the 4 lanes of each quad via quad_perm DPP (VALU pipe, no DS ops).
__device__ __forceinline__ float quad_sum(float p) {
    int q;
    q = __builtin_amdgcn_update_dpp(0, __float_as_int(p), 0xB1, 0xF, 0xF, false); // xor 1
    p += __int_as_float(q);
    q = __builtin_amdgcn_update_dpp(0, __float_as_int(p), 0x4E, 0xF, 0xF, false); // xor 2
    p += __int_as_float(q);
    return p;
}

// ---------------------------------------------------------------------------
// bf16 MFMA NT GEMM: C[M,N] = sum_k A[m,k]*B[n,k].
// 128x128 tile, BK=64, 256 threads (4 waves 2x2), 4x4 16x16x32 frags/wave.
// Epilogues: 0 = plain store; 1 = x_proj split (dt_lr bf16 / BC fp32);
//            2 = softplus(acc + bias[col]) -> bf16
// ---------------------------------------------------------------------------
template <int EPI, typename TC>
__global__ __launch_bounds__(256) void gemm_mfma_nt(
    const bf16* __restrict__ A, const bf16* __restrict__ B,
    TC* __restrict__ C, int M, int N, int K, int lda, int ldb, int ldc,
    const float* __restrict__ bias, bf16* __restrict__ aux,
    float* __restrict__ aux2)
{
    __shared__ bf16 As[128][64];   // 16 KB
    __shared__ bf16 Bs[128][64];   // 16 KB

    const int tid  = threadIdx.x;
    const int lane = tid & 63;
    const int wave = tid >> 6;          // 0..3
    const int wm   = (wave >> 1) * 64;
    const int wn   = (wave & 1) * 64;

    const int m0 = blockIdx.x * 128;
    const int n0 = blockIdx.y * 128;

    f32x4 acc[4][4] = {};

    const int srow = lane >> 3;
    const int scol = (lane & 7) * 8;

    for (int k0 = 0; k0 < K; k0 += 64) {
        __syncthreads();
#pragma unroll
        for (int i = 0; i < 4; ++i) {
            int seg = wave * 4 + i;
            int row = seg * 8 + srow;
            async_cp16(A + (size_t)(m0 + row) * lda + k0 + scol, &As[seg * 8][0]);
            async_cp16(B + (size_t)(n0 + row) * ldb + k0 + scol, &Bs[seg * 8][0]);
        }
        __syncthreads();

#pragma unroll
        for (int kk = 0; kk < 64; kk += 32) {
            short8 a[4], b[4];
            const int fr = lane & 15;
            const int fk = kk + (lane >> 4) * 8;
#pragma unroll
            for (int i = 0; i < 4; ++i) {
                a[i] = *(const short8*)&As[wm + i * 16 + fr][fk];
                b[i] = *(const short8*)&Bs[wn + i * 16 + fr][fk];
            }
#pragma unroll
            for (int i = 0; i < 4; ++i)
#pragma unroll
                for (int j = 0; j < 4; ++j)
                    acc[i][j] = __builtin_amdgcn_mfma_f32_16x16x32_bf16(
                        a[i], b[j], acc[i][j], 0, 0, 0);
        }
    }

    // C/D: col = lane&15, row = (lane>>4)*4 + reg   [m89-verified]
#pragma unroll
    for (int i = 0; i < 4; ++i) {
        int row = m0 + wm + i * 16 + (lane >> 4) * 4;
#pragma unroll
        for (int j = 0; j < 4; ++j) {
            int col = n0 + wn + j * 16 + (lane & 15);
#pragma unroll
            for (int r = 0; r < 4; ++r) {
                float v = acc[i][j][r];
                if (EPI == 0) {
                    st1(C + (size_t)(row + r) * ldc + col, v);
                } else if (EPI == 1) {
                    if (col < DT_RANK)
                        aux[(size_t)(row + r) * DT_RANK + col] = f2bf(v);
                    else if (col < DT_RANK + 2 * D_STATE)
                        aux2[(size_t)(row + r) * (2 * D_STATE) + (col - DT_RANK)] = v;
                } else {  // EPI == 2: softplus(acc + bias)
                    float x  = v + bias[col];
                    float sp = fmaxf(x, 0.f) + __logf(1.f + __expf(-fabsf(x)));
                    ((bf16*)C)[(size_t)(row + r) * ldc + col] = f2bf(sp);
                }
            }
        }
    }
}

// ---------------------------------------------------------------------------
// fp32 -> bf16 conversion (4 elems/thread); n must be a multiple of 1024.
// ---------------------------------------------------------------------------
__global__ void cvt_f32_bf16(const float* __restrict__ src,
                             bf16* __restrict__ dst, int n)
{
    int i = (blockIdx.x * blockDim.x + threadIdx.x) * 4;
    if (i >= n) return;
    float4 v = *(const float4*)(src + i);
    bf16 o[4] = { f2bf(v.x), f2bf(v.y), f2bf(v.z), f2bf(v.w) };
    *(ushort4*)(dst + i) = *(ushort4*)o;
}

// W_x (160 x 4096 fp32) -> zero-padded 256 x 4096 bf16
__global__ void cvt_pad_wx(const float* __restrict__ src, bf16* __restrict__ dst)
{
    int i = (blockIdx.x * blockDim.x + threadIdx.x) * 4;
    if (i >= 256 * D_INNER) return;
    int row = i / D_INNER;
    bf16 o[4] = {};
    if (row < DT_RANK + 2 * D_STATE) {
        float4 v = *(const float4*)(src + i);
        o[0] = f2bf(v.x); o[1] = f2bf(v.y); o[2] = f2bf(v.z); o[3] = f2bf(v.w);
    }
    *(ushort4*)(dst + i) = *(ushort4*)o;
}

// ---------------------------------------------------------------------------
// Depthwise causal conv1d (width 4) + bias + SiLU.  8 channels/thread,
// short8 vector loads/stores, fp32 math.
// ---------------------------------------------------------------------------
__global__ void conv_silu(const bf16* __restrict__ X,
                          const float* __restrict__ conv_w,
                          const float* __restrict__ conv_b,
                          bf16* __restrict__ xact)
{
    unsigned idx = blockIdx.x * blockDim.x + threadIdx.x;   // one per 8 channels
    if (idx >= (unsigned)BL * (D_INNER / 8)) return;
    int c8 = (idx & (D_INNER / 8 - 1)) * 8;
    unsigned bl = idx >> 9;                // D_INNER/8 = 512
    int l = bl & (SEQLEN - 1);
    int b = bl >> 11;

    float acc[8];
    float4 wv[8];
#pragma unroll
    for (int j = 0; j < 8; ++j) {
        acc[j] = conv_b[c8 + j];
        wv[j]  = *(const float4*)(conv_w + (c8 + j) * 4);
    }
#pragma unroll
    for (int t = 0; t < D_CONV; ++t) {
        int ll = l - (D_CONV - 1) + t;
        if (ll >= 0) {
            short8 xv = *(const short8*)(X + ((size_t)b * SEQLEN + ll) * D_INNER + c8);
#pragma unroll
            for (int j = 0; j < 8; ++j)
                acc[j] = fmaf(us2f((unsigned short)xv[j]), (&wv[j].x)[t], acc[j]);
        }
    }
    bf16 o[8];
#pragma unroll
    for (int j = 0; j < 8; ++j)
        o[j] = f2bf(acc[j] * fast_rcp(1.f + __expf(-acc[j])));
    *(short8*)(xact + (size_t)bl * D_INNER + c8) = *(short8*)o;
}

// ---------------------------------------------------------------------------
// Chunked selective scan, v2: 4 lanes/channel (4 states each).
//  - u/delta/z staged in LDS via global_load_lds (double-buffered tiles)
//  - B/C read directly from global as float4 (BCbuf is 1 MB -> L2-resident);
//    keeps them OFF the DS pipe (previous version was DS-pipe-bound: ~45
//    DS-cyc/wave-step == the measured 310 us)
//  - p-reduce across 4 lanes via quad_perm DPP (VALU pipe, zero DS ops)
// Block = 256 thr (4 waves) owns 64 channels.
// ---------------------------------------------------------------------------
__global__ __launch_bounds__(256, 4) void scan_part1(
    const bf16* __restrict__ U,      // xact   (BL, D_INNER)
    const bf16* __restrict__ DLT,    // delta  (BL, D_INNER)
    const float* __restrict__ BC,    // (BL, 32): B[16] then C[16]
    const float* __restrict__ A_log,
    float4* __restrict__ Hscr,       // (NCHUNK-1, BATCH, D_INNER, 4)
    float*  __restrict__ Sscr)       // (NCHUNK-1, BATCH, D_INNER)
{
    __shared__ unsigned short Us[2][SCH][64];   // 8 KB
    __shared__ unsigned short Ds[2][SCH][64];   // 8 KB

    const int b    = blockIdx.y;
    const int c    = blockIdx.z;               // chunk 0..NCHUNK-2
    const int d0   = blockIdx.x * 64;
    const int lane = threadIdx.x & 63;
    const int wave = threadIdx.x >> 6;
    const int sub  = lane & 3;                 // states 4sub..4sub+3
    const int grp  = lane >> 2;                // 0..15
    const int ci   = wave * 16 + grp;          // channel within block (0..63)
    const int d    = d0 + ci;

    const float4 al = *(const float4*)&A_log[(size_t)d * D_STATE + 4 * sub];
    const float A0 = -__expf(al.x), A1 = -__expf(al.y),
                A2 = -__expf(al.z), A3 = -__expf(al.w);

    const size_t base = (size_t)b * SEQLEN + (size_t)c * CHUNK;

    const int sr = lane >> 3;                  // 0..7 (row within 8-row seg)
    const int sc = (lane & 7) * 8;             // channel offset (16 B)

    auto stage = [&](int bb, int l0) {
        if (wave == 0) {
#pragma unroll
            for (int i = 0; i < 4; ++i) {
                int row = i * 8 + sr;
                async_cp16(U + (base + l0 + row) * (size_t)D_INNER + d0 + sc,
                           &Us[bb][i * 8][0]);
            }
        } else if (wave == 1) {
#pragma unroll
            for (int i = 0; i < 4; ++i) {
                int row = i * 8 + sr;
                async_cp16(DLT + (base + l0 + row) * (size_t)D_INNER + d0 + sc,
                           &Ds[bb][i * 8][0]);
            }
        }
    };

    float h0 = 0.f, h1 = 0.f, h2 = 0.f, h3 = 0.f, sdl = 0.f;

    stage(0, 0);
    __syncthreads();   // tile 0 resident

    for (int t = 0; t < NTILE; ++t) {
        const int cur = t & 1, nxt = cur ^ 1;
        if (t + 1 < NTILE) stage(nxt, (t + 1) * SCH);

#pragma unroll 8
        for (int l = 0; l < SCH; ++l) {
            float u  = us2f(Us[cur][l][ci]);
            float dl = us2f(Ds[cur][l][ci]);
            float4 Bv = *(const float4*)(BC + (base + t * SCH + l) * (2 * D_STATE)
                                         + 4 * sub);
            float du = dl * u;
            h0 = fmaf(h0, __expf(dl * A0), du * Bv.x);
            h1 = fmaf(h1, __expf(dl * A1), du * Bv.y);
            h2 = fmaf(h2, __expf(dl * A2), du * Bv.z);
            h3 = fmaf(h3, __expf(dl * A3), du * Bv.w);
            sdl += dl;
        }
        __syncthreads();
    }

    const size_t idx = (size_t)(c * BATCH + b) * D_INNER + d;
    Hscr[idx * 4 + sub] = make_float4(h0, h1, h2, h3);
    if (sub == 0) Sscr[idx] = sdl;
}

__global__ void scan_combine(float4* __restrict__ Hscr,
                             const float* __restrict__ Sscr,
                             const float* __restrict__ A_log)
{
    int tid = blockIdx.x * blockDim.x + threadIdx.x;   // (b, d, sub)
    if (tid >= BATCH * D_INNER * 4) return;
    const int sub = tid & 3;
    const int d   = (tid >> 2) & (D_INNER - 1);
    const int b   = tid >> 14;

    const float4 al = *(const float4*)&A_log[(size_t)d * D_STATE + 4 * sub];
    const float A0 = -__expf(al.x), A1 = -__expf(al.y),
                A2 = -__expf(al.z), A3 = -__expf(al.w);

    float H0 = 0.f, H1 = 0.f, H2 = 0.f, H3 = 0.f;
#pragma unroll
    for (int c = 0; c < NCHUNK - 1; ++c) {
        const size_t idx = (size_t)(c * BATCH + b) * D_INNER + d;
        float4 hl = Hscr[idx * 4 + sub];
        float  s  = Sscr[idx];
        // Hinit[c+1] = hL[c] + exp(A*sum_dl[c]) * Hinit[c]; store at slot c
        H0 = fmaf(H0, __expf(A0 * s), hl.x);
        H1 = fmaf(H1, __expf(A1 * s), hl.y);
        H2 = fmaf(H2, __expf(A2 * s), hl.z);
        H3 = fmaf(H3, __expf(A3 * s), hl.w);
        Hscr[idx * 4 + sub] = make_float4(H0, H1, H2, H3);
    }
}

__global__ __launch_bounds__(256, 4) void scan_main(
    const bf16* __restrict__ U,      // xact   (BL, D_INNER)
    const bf16* __restrict__ DLT,    // delta  (BL, D_INNER)
    const bf16* __restrict__ Z,      // z      (BL, D_INNER)
    const float* __restrict__ BC,    // (BL, 32): B[16] then C[16]
    const float* __restrict__ A_log,
    const float* __restrict__ Dp,
    const float4* __restrict__ Hscr, // chunk init states (slot c-1 for chunk c)
    bf16* __restrict__ Y)            // output y (may alias Z)
{
    __shared__ unsigned short Us[2][SCH][64];   // 8 KB
    __shared__ unsigned short Ds[2][SCH][64];   // 8 KB
    __shared__ unsigned short Zs[2][SCH][64];   // 8 KB

    const int b    = blockIdx.y;
    const int c    = blockIdx.z;               // chunk 0..NCHUNK-1
    const int d0   = blockIdx.x * 64;
    const int lane = threadIdx.x & 63;
    const int wave = threadIdx.x >> 6;
    const int sub  = lane & 3;
    const int grp  = lane >> 2;
    const int ci   = wave * 16 + grp;
    const int d    = d0 + ci;

    const float4 al = *(const float4*)&A_log[(size_t)d * D_STATE + 4 * sub];
    const float A0 = -__expf(al.x), A1 = -__expf(al.y),
                A2 = -__expf(al.z), A3 = -__expf(al.w);
    const float Dv = Dp[d];

    const size_t base = (size_t)b * SEQLEN + (size_t)c * CHUNK;

    const int sr = lane >> 3;
    const int sc = (lane & 7) * 8;

    auto stage = [&](int bb, int l0) {
        if (wave == 0) {
#pragma unroll
            for (int i = 0; i < 4; ++i) {
                int row = i * 8 + sr;
                async_cp16(U + (base + l0 + row) * (size_t)D_INNER + d0 + sc,
                           &Us[bb][i * 8][0]);
            }
        } else if (wave == 1) {
#pragma unroll
            for (int i = 0; i < 4; ++i) {
                int row = i * 8 + sr;
                async_cp16(DLT + (base + l0 + row) * (size_t)D_INNER + d0 + sc,
                           &Ds[bb][i * 8][0]);
            }
        } else if (wave == 2) {
#pragma unroll
            for (int i = 0; i < 4; ++i) {
                int row = i * 8 + sr;
                async_cp16(Z + (base + l0 + row) * (size_t)D_INNER + d0 + sc,
                           &Zs[bb][i * 8][0]);
            }
        }
    };

    float h0 = 0.f, h1 = 0.f, h2 = 0.f, h3 = 0.f;
    if (c > 0) {
        float4 hi = Hscr[((size_t)((c - 1) * BATCH + b) * D_INNER + d) * 4 + sub];
        h0 = hi.x; h1 = hi.y; h2 = hi.z; h3 = hi.w;
    }

    stage(0, 0);
    __syncthreads();   // tile 0 resident

    for (int t = 0; t < NTILE; ++t) {
        const int cur = t & 1, nxt = cur ^ 1;
        if (t + 1 < NTILE) stage(nxt, (t + 1) * SCH);

#pragma unroll 8
        for (int l = 0; l < SCH; ++l) {
            float u  = us2f(Us[cur][l][ci]);
            float dl = us2f(Ds[cur][l][ci]);
            const float* bcp = BC + (base + t * SCH + l) * (2 * D_STATE);
            float4 Bv = *(const float4*)(bcp + 4 * sub);
            float4 Cv = *(const float4*)(bcp + D_STATE + 4 * sub);
            float du = dl * u;
            h0 = fmaf(h0, __expf(dl * A0), du * Bv.x);
            h1 = fmaf(h1, __expf(dl * A1), du * Bv.y);
            h2 = fmaf(h2, __expf(dl * A2), du * Bv.z);
            h3 = fmaf(h3, __expf(dl * A3), du * Bv.w);
            float p = fmaf(h3, Cv.w, fmaf(h2, Cv.z, fmaf(h1, Cv.y, h0 * Cv.x)));
            p = quad_sum(p);
            if (sub == 0) {
                float z = us2f(Zs[cur][l][ci]);
                float g = z * fast_rcp(1.f + __expf(-z));
                Y[(base + t * SCH + l) * (size_t)D_INNER + d] =
                    f2bf((p + Dv * u) * g);
            }
        }
        __syncthreads();   // all waves done with cur; nxt stage drained
    }
}

// ---------------------------------------------------------------------------
// Workspace (total exactly 139,460,608 B — proven safe):
//   buf1  [  0,  64Mi) bf16 : X -> delta -> W_out_bf16
//   buf2  [64Mi, 128Mi) bf16 : Z -> y (in place, via scan)
//   tail  [128Mi, +5MiB): BCbuf fp32 (1 MiB) | dtlr bf16 (2 MiB) |
//                         wxp bf16 (2 MiB; W_dt bf16 reuses it)
//   After phase 4 the dtlr+wxp 4 MiB region is dead -> chunked-scan scratch
//   (Hscr 3 MiB + Sscr 0.19 MiB) lives there.
// d_out doubles as scratch: hs_bf16 (32 MiB) + W_in_bf16 (32 MiB) during
// in_proj; then xact bf16 (64 MiB) until out_proj writes the final fp32.
// ---------------------------------------------------------------------------
extern "C" void kernel_launch(void* const* d_in, const int* in_sizes, int n_in,
                              void* d_out, int out_size, void* d_ws, size_t ws_size,
                              hipStream_t stream)
{
    const float* hs      = (const float*)d_in[0];
    const float* W_in    = (const float*)d_in[1];
    const float* conv_w  = (const float*)d_in[2];
    const float* conv_b  = (const float*)d_in[3];
    const float* W_x     = (const float*)d_in[4];
    const float* W_dt    = (const float*)d_in[5];
    const float* dt_bias = (const float*)d_in[6];
    const float* A_log   = (const float*)d_in[7];
    const float* Dp      = (const float*)d_in[8];
    const float* W_out   = (const float*)d_in[9];
    float* out = (float*)d_out;

    const size_t nBig = (size_t)BL * D_INNER;            // 33,554,432
    const size_t need = 2 * nBig * sizeof(bf16)
                      + (size_t)BL * 160 * sizeof(float);
    if (ws_size < need) {
        hipMemsetAsync(d_out, 0, (size_t)out_size * sizeof(float), stream);
        return;
    }

    bf16*  buf1  = (bf16*)d_ws;                          // 64 MiB
    bf16*  buf2  = buf1 + nBig;                          // 64 MiB
    float* BCbuf = (float*)(buf2 + nBig);                // 1 MiB (BL x 32 fp32)
    bf16*  dtlr  = (bf16*)(BCbuf + (size_t)BL * 2 * D_STATE); // 2 MiB
    bf16*  wxp   = dtlr + (size_t)BL * DT_RANK;          // 2 MiB
    bf16*  wdtb  = wxp;                                  // reuse (phase 4)

    // chunked-scan scratch overlays dtlr+wxp (dead after phase 4): 3.3 MiB
    float4* Hscr = (float4*)dtlr;
    float*  Sscr = (float*)(Hscr + (size_t)(NCHUNK - 1) * BATCH * D_INNER * 4);

    const int nHS = BL * D_MODEL;                        // 16,777,216
    const int nWI = 2 * D_INNER * D_MODEL;               // 16,777,216
    const int nWH = D_INNER * D_MODEL;                   // 8,388,608
    bf16* hsb  = (bf16*)d_out;                           // 32 MiB
    bf16* wb   = hsb + nHS;                              // 32 MiB
    bf16* xact = (bf16*)d_out;                           // after hsb/wb die

    // --- Phase 1: in_proj (bf16 MFMA) ------------------------------------
    cvt_f32_bf16<<<nHS / 1024, 256, 0, stream>>>(hs, hsb, nHS);
    cvt_f32_bf16<<<nWI / 1024, 256, 0, stream>>>(W_in, wb, nWI);
    gemm_mfma_nt<0, bf16><<<dim3(BL / 128, D_INNER / 128), 256, 0, stream>>>(
        hsb, wb + (size_t)nWH, buf2, BL, D_INNER, D_MODEL,
        D_MODEL, D_MODEL, D_INNER, nullptr, nullptr, nullptr);
    gemm_mfma_nt<0, bf16><<<dim3(BL / 128, D_INNER / 128), 256, 0, stream>>>(
        hsb, wb, buf1, BL, D_INNER, D_MODEL,
        D_MODEL, D_MODEL, D_INNER, nullptr, nullptr, nullptr);

    // --- Phase 2: conv + SiLU -> xact (d_out; hsb/wb dead) ---------------
    conv_silu<<<(BL * (D_INNER / 8)) / 256, 256, 0, stream>>>(
        buf1, conv_w, conv_b, xact);

    // --- Phase 3: x_proj (MFMA, padded N=256) -> dtlr bf16 + BCbuf fp32 --
    cvt_pad_wx<<<(256 * D_INNER) / 1024, 256, 0, stream>>>(W_x, wxp);
    gemm_mfma_nt<1, float><<<dim3(BL / 128, 2), 256, 0, stream>>>(
        xact, wxp, (float*)nullptr, BL, 256, D_INNER,
        D_INNER, D_INNER, 0, nullptr, dtlr, BCbuf);

    // --- Phase 4: dt_proj (MFMA) + fused softplus(+bias) -> delta (buf1) -
    cvt_f32_bf16<<<(D_INNER * DT_RANK) / 1024, 256, 0, stream>>>(W_dt, wdtb,
                                                                 D_INNER * DT_RANK);
    gemm_mfma_nt<2, bf16><<<dim3(BL / 128, D_INNER / 128), 256, 0, stream>>>(
        dtlr, wdtb, buf1, BL, D_INNER, DT_RANK,
        DT_RANK, DT_RANK, D_INNER, dt_bias, nullptr, nullptr);

    // --- Phase 5: chunked scan (silu(z) fused) -> y in buf2 --------------
    scan_part1<<<dim3(D_INNER / 64, BATCH, NCHUNK - 1), 256, 0, stream>>>(
        xact, buf1, BCbuf, A_log, Hscr, Sscr);
    scan_combine<<<(BATCH * D_INNER * 4) / 256, 256, 0, stream>>>(
        Hscr, Sscr, A_log);
    scan_main<<<dim3(D_INNER / 64, BATCH, NCHUNK), 256, 0, stream>>>(
        xact, buf1, buf2, BCbuf, A_log, Dp, Hscr, buf2);

    // --- Phase 6: out_proj (MFMA).  W_out -> buf1 (delta dead) -----------
    cvt_f32_bf16<<<nWH / 1024, 256, 0, stream>>>(W_out, buf1, nWH);
    gemm_mfma_nt<0, float><<<dim3(BL / 128, D_MODEL / 128), 256, 0, stream>>>(
        buf2, buf1, out, BL, D_MODEL, D_INNER,
        D_INNER, D_INNER, D_MODEL, nullptr, nullptr, nullptr);
}